// Round 4
// baseline (125.805 us; speedup 1.0000x reference)
//
#include <hip/hip_runtime.h>

typedef __attribute__((ext_vector_type(8))) short s16x8;
typedef __attribute__((ext_vector_type(4))) float f32x4;
typedef __attribute__((ext_vector_type(4))) unsigned int u32x4;
typedef __attribute__((ext_vector_type(2))) unsigned int u32x2;
typedef unsigned short u16;
typedef unsigned int u32;

#define LOG2E 1.4426950408889634f

__device__ __forceinline__ u16 f2bf(float x) {
  u32 u = __float_as_uint(x);
  u += 0x7FFFu + ((u >> 16) & 1u);
  return (u16)(u >> 16);
}

__device__ __forceinline__ u32 pack_bf_trunc(float lo, float hi) {
  return (__float_as_uint(lo) >> 16) | (__float_as_uint(hi) & 0xFFFF0000u);
}

__device__ __forceinline__ void gl_lds16(const void* g, void* l) {
  __builtin_amdgcn_global_load_lds((const __attribute__((address_space(1))) void*)g,
                                   (__attribute__((address_space(3))) void*)l, 16, 0, 0);
}

#define MFMA16(a, b, c) __builtin_amdgcn_mfma_f32_16x16x32_bf16((a), (b), (c), 0, 0, 0)

// ---------------- fused prep kernel ----------------

__global__ __launch_bounds__(256) void prep(const float* __restrict__ hs,
                                            const float* __restrict__ Wq,
                                            const float* __restrict__ Wk,
                                            const float* __restrict__ Wv,
                                            const float* __restrict__ Wo,
                                            const float* __restrict__ tbl,
                                            u16* __restrict__ hsb,
                                            u16* __restrict__ wt,
                                            u16* __restrict__ wot,
                                            float* __restrict__ biasT) {
  const int blk = blockIdx.x;
  const int tid = threadIdx.x;
  if (blk < 2048) {
    const int i = blk * 256 + tid;
    const float4* s4 = (const float4*)hs;
    float4 a = s4[i * 2];
    float4 b = s4[i * 2 + 1];
    s16x8 o;
    o[0] = (short)f2bf(a.x); o[1] = (short)f2bf(a.y);
    o[2] = (short)f2bf(a.z); o[3] = (short)f2bf(a.w);
    o[4] = (short)f2bf(b.x); o[5] = (short)f2bf(b.y);
    o[6] = (short)f2bf(b.z); o[7] = (short)f2bf(b.w);
    *(s16x8*)&hsb[i * 8] = o;
  } else if (blk < 4096) {
    int r = blk - 2048;
    const int sel = r >> 9;
    r &= 511;
    const float* W = sel == 0 ? Wq : (sel == 1 ? Wk : (sel == 2 ? Wv : Wo));
    u16* dst = sel == 3 ? wot : wt + sel * 1048576;
    const int n = (r & 15) * 64 + (tid & 63);
    const int kb = (r >> 4) * 32 + (tid >> 6) * 8;
    s16x8 o;
#pragma unroll
    for (int j = 0; j < 8; ++j) o[j] = (short)f2bf(W[(kb + j) * 1024 + n]);
    *(s16x8*)&dst[n * 1024 + kb] = o;
  } else {
    const int i = (blk - 4096) * 256 + tid;
    const int h = i >> 12, dp = i & 4095;
    const int delta = dp - 2047;
    const int rp = delta < 0 ? -delta : delta;
    int bucket = delta > 0 ? 16 : 0;
    if (rp < 8)
      bucket += rp;
    else
      bucket += 8 + (rp >= 12) + (rp >= 16) + (rp >= 23) + (rp >= 32) +
                (rp >= 46) + (rp >= 64) + (rp >= 91);
    biasT[i] = tbl[bucket * 16 + h] * LOG2E;
  }
}

// VT[(bh*64+d)*2048 + s] = V[(b*2048+s)*1024 + h*64 + d]
__global__ __launch_bounds__(256) void vtrans(const u16* __restrict__ V,
                                              u16* __restrict__ VT) {
  const int tid = threadIdx.x;
  const int bh = blockIdx.y;
  const int b = bh >> 4, h = bh & 15;
  const int s0 = blockIdx.x * 32;
  const int d = tid & 63;
  const int si = tid >> 6;
  s16x8 o;
#pragma unroll
  for (int j = 0; j < 8; ++j)
    o[j] = (short)V[(b * 2048 + s0 + si * 8 + j) * 1024 + h * 64 + d];
  *(s16x8*)&VT[(bh * 64 + d) * 2048 + s0 + si * 8] = o;
}

// ---------------- GEMM core: C[128x128] tile, A[M,1024] @ Bt[N,1024]^T ----------------

__device__ __forceinline__ void gemm_core(const u16* __restrict__ A,
                                          const u16* __restrict__ Bt,
                                          int m0, int n0,
                                          u16* As, u16* Bs, f32x4 acc[4][4]) {
  const int tid = threadIdx.x;
  const int w = tid >> 6, l = tid & 63, g = l >> 4, m15 = l & 15;
  const int wr = (w >> 1) * 64, wc = (w & 1) * 64;
#pragma unroll
  for (int i = 0; i < 4; ++i)
#pragma unroll
    for (int j = 0; j < 4; ++j) acc[i][j] = (f32x4){0.f, 0.f, 0.f, 0.f};

  for (int kt = 0; kt < 16; ++kt) {
    const int k0 = kt * 64;
    __syncthreads();
#pragma unroll
    for (int c = 0; c < 4; ++c) {
      const int idx = c * 256 + tid;
      const int row = idx >> 3, col16 = idx & 7;
      const int scol = col16 ^ (row & 7);
      gl_lds16(&A[(m0 + row) * 1024 + k0 + scol * 8], (char*)As + c * 4096 + w * 1024);
      gl_lds16(&Bt[(n0 + row) * 1024 + k0 + scol * 8], (char*)Bs + c * 4096 + w * 1024);
    }
    __syncthreads();
#pragma unroll
    for (int ks = 0; ks < 2; ++ks) {
      s16x8 af[4], bf[4];
#pragma unroll
      for (int mf = 0; mf < 4; ++mf) {
        const int row = wr + mf * 16 + m15;
        af[mf] = *(const s16x8*)&As[(row * 8 + ((ks * 4 + g) ^ (row & 7))) * 8];
      }
#pragma unroll
      for (int nf = 0; nf < 4; ++nf) {
        const int row = wc + nf * 16 + m15;
        bf[nf] = *(const s16x8*)&Bs[(row * 8 + ((ks * 4 + g) ^ (row & 7))) * 8];
      }
#pragma unroll
      for (int mf = 0; mf < 4; ++mf)
#pragma unroll
        for (int nf = 0; nf < 4; ++nf)
          acc[mf][nf] = MFMA16(af[mf], bf[nf], acc[mf][nf]);
    }
  }
}

// QKV: grid 768 blocks 1D, XCD-chunked (8m x 12n per XCD)
__global__ __launch_bounds__(256) void gemm_qkv(const u16* __restrict__ X,
                                                const u16* __restrict__ Wt,
                                                u16* __restrict__ Q,
                                                u16* __restrict__ Kb,
                                                u16* __restrict__ Vb) {
  __shared__ u16 As[8192], Bs[8192];
  f32x4 acc[4][4];
  const int flat = blockIdx.x;
  const int x = flat & 7, i = flat >> 3;  // i in [0,96)
  const int m0 = ((x & 3) * 8 + (i & 7)) * 128;
  const int n0 = ((x >> 2) * 12 + (i >> 3)) * 128;
  gemm_core(X, Wt, m0, n0, As, Bs, acc);

  const int tid = threadIdx.x;
  const int w = tid >> 6, l = tid & 63, g = l >> 4, m15 = l & 15;
  const int wr = (w >> 1) * 64, wc = (w & 1) * 64;
  const int nsel = n0 >> 10;
  u16* dst = nsel == 0 ? Q : (nsel == 1 ? Kb : Vb);
  const float scale = nsel == 0 ? 0.125f * LOG2E : 1.0f;
  const int ncol0 = (n0 & 1023) + wc;
#pragma unroll
  for (int mf = 0; mf < 4; ++mf) {
    const int rbase = m0 + wr + mf * 16 + g * 4;
#pragma unroll
    for (int nf = 0; nf < 4; ++nf) {
      const int col = ncol0 + nf * 16 + m15;
#pragma unroll
      for (int r = 0; r < 4; ++r)
        dst[(rbase + r) * 1024 + col] = f2bf(acc[mf][nf][r] * scale);
    }
  }
}

// out-proj: grid 256 blocks 1D, XCD-chunked (8m x 4n per XCD)
__global__ __launch_bounds__(256) void gemm_out(const u16* __restrict__ CTX,
                                                const u16* __restrict__ Wot,
                                                float* __restrict__ Out) {
  __shared__ u16 As[8192], Bs[8192];
  f32x4 acc[4][4];
  const int flat = blockIdx.x;
  const int x = flat & 7, i = flat >> 3;  // i in [0,32)
  const int m0 = ((x & 3) * 8 + (i & 7)) * 128;
  const int n0 = ((x >> 2) * 4 + (i >> 3)) * 128;
  gemm_core(CTX, Wot, m0, n0, As, Bs, acc);

  const int tid = threadIdx.x;
  const int w = tid >> 6, l = tid & 63, g = l >> 4, m15 = l & 15;
  const int wr = (w >> 1) * 64, wc = (w & 1) * 64;
#pragma unroll
  for (int mf = 0; mf < 4; ++mf) {
    const int rbase = m0 + wr + mf * 16 + g * 4;
#pragma unroll
    for (int nf = 0; nf < 4; ++nf) {
      const int col = n0 + wc + nf * 16 + m15;
#pragma unroll
      for (int r = 0; r < 4; ++r)
        Out[(rbase + r) * 1024 + col] = acc[mf][nf][r];
    }
  }
}

// ---------------- flash attention v4 ----------------
// 1 block = (b, h, 128 q-rows); 4 waves x 32 q-rows. KV tiles of 64, dbuf.
// Swapped QK^T: S^T = mfma(K_frag, Q_frag); lane holds q=qs*16+m15 (fixed),
// kv=c*16+g*4+r. P redistributed to the PV A-fragment ENTIRELY IN REGISTERS:
// pack bf16 pairs, then permlane32_swap + permlane16_swap (CDNA4) route
// quarter-rows so lane (g,m15) ends with P[q][kv=ks*32+g*8+j]. No P LDS, no
// bank conflicts, shorter QK->PV critical path. No-max exp2 softmax; bias as
// accumulator init; ls via ones-MFMA.

__global__ __launch_bounds__(256, 2) void attn_kernel(const u16* __restrict__ Qg,
                                                      const u16* __restrict__ Kg,
                                                      const u16* __restrict__ VTg,
                                                      const float* __restrict__ biasT,
                                                      const float* __restrict__ tbl,
                                                      u16* __restrict__ CTX) {
  __shared__ u16 KT[2][4096];   // [64 kv][64 kdim] swizzled, dbuf
  __shared__ u16 VTs[2][4096];  // [64 dv][64 kv]  swizzled, dbuf

  const int tid = threadIdx.x;
  const int w = tid >> 6, l = tid & 63, g = l >> 4, m15 = l & 15;
  // XCD-chunked remap: 512 blocks; each XCD gets 4 whole (b,h) K/V sets
  const int flat = blockIdx.x;
  const int nf_ = (flat & 7) * 64 + (flat >> 3);
  const int qblk = nf_ & 15, bh = nf_ >> 4;
  const int b = bh >> 4, h = bh & 15;
  const int qw = qblk * 128 + w * 32;  // this wave's q base (32 rows)

  const float fpos = tbl[31 * 16 + h] * LOG2E;  // delta >= 91 bucket
  const float fneg = tbl[15 * 16 + h] * LOG2E;  // delta <= -91 bucket

  // Q fragments, B-operand layout (col=q=m15, k=ks*32+g*8+j), 2 q-subfrags
  s16x8 aq[2][2];
#pragma unroll
  for (int qs = 0; qs < 2; ++qs) {
    const u16* qp = &Qg[(b * 2048 + qw + qs * 16 + m15) * 1024 + h * 64 + g * 8];
    aq[qs][0] = *(const s16x8*)qp;
    aq[qs][1] = *(const s16x8*)(qp + 32);
  }

  s16x8 vone;
#pragma unroll
  for (int j = 0; j < 8; ++j) vone[j] = (short)0x3F80;  // bf16 1.0

  f32x4 o[2][4];
  f32x4 ls4[2];
#pragma unroll
  for (int qs = 0; qs < 2; ++qs) {
    ls4[qs] = (f32x4){0.f, 0.f, 0.f, 0.f};
#pragma unroll
    for (int d = 0; d < 4; ++d) o[qs][d] = (f32x4){0.f, 0.f, 0.f, 0.f};
  }

  const u16* Kbase = &Kg[(b * 2048) * 1024 + h * 64];
  const u16* Vbase = &VTg[bh * 64 * 2048];

#define STAGE(buf, kv0)                                                          \
  {                                                                              \
    _Pragma("unroll") for (int c = 0; c < 2; ++c) {                              \
      const int idx = c * 256 + tid;                                             \
      const int row = idx >> 3, col16 = idx & 7;                                 \
      const int scol = col16 ^ (row & 7);                                        \
      gl_lds16(&Kbase[(kv0 + row) * 1024 + scol * 8],                            \
               (char*)KT + (buf)*8192 + c * 4096 + w * 1024);                    \
      gl_lds16(&Vbase[row * 2048 + (kv0) + scol * 8],                            \
               (char*)VTs + (buf)*8192 + c * 4096 + w * 1024);                   \
    }                                                                            \
  }

  STAGE(0, 0);
  int cur = 0;
  for (int t = 0; t < 32; ++t) {
    const int kv0 = t * 64;
    __syncthreads();  // drains vmcnt: buf[cur] ready; buf[cur^1] free
    if (t < 31) STAGE(cur ^ 1, kv0 + 64);

    const u16* KTc = &KT[cur][0];
    const u16* VTc = &VTs[cur][0];

    // S^T accumulators init with bias; lane: q=qs*16+m15, kv=c*16+g*4+r
    f32x4 s[2][4];
    const int diff = kv0 - qw;
    if (diff <= -160 || diff >= 128) {
      const float bc = diff > 0 ? fpos : fneg;
#pragma unroll
      for (int qs = 0; qs < 2; ++qs)
#pragma unroll
        for (int c = 0; c < 4; ++c) s[qs][c] = (f32x4){bc, bc, bc, bc};
    } else {
#pragma unroll
      for (int qs = 0; qs < 2; ++qs) {
        const float* bp = &biasT[h * 4096 + kv0 + g * 4 - qw - qs * 16 - m15 + 2047];
#pragma unroll
        for (int c = 0; c < 4; ++c)
#pragma unroll
          for (int r = 0; r < 4; ++r) s[qs][c][r] = bp[c * 16 + r];
      }
    }

    // S^T += K Q^T  (A = K-frag, B = Q-frag; 8 LDS reads feed 16 MFMAs)
#pragma unroll
    for (int ks = 0; ks < 2; ++ks) {
#pragma unroll
      for (int c = 0; c < 4; ++c) {
        const int row = c * 16 + m15;
        const s16x8 bk = *(const s16x8*)&KTc[(row * 8 + ((ks * 4 + g) ^ (row & 7))) * 8];
        s[0][c] = MFMA16(bk, aq[0][ks], s[0][c]);
        s[1][c] = MFMA16(bk, aq[1][ks], s[1][c]);
      }
    }

    // p = exp2(s); pack bf16 pairs; in-register quarter-row redistribution:
    // dword d of pa[qs][ks] = w_{d&1?23:01}[2ks+(g>>1)] from lane (2(g&1)+(d>>1), m15).
    // permlane32_swap(X,Y) -> {X.lo,Y.lo},{X.hi,Y.hi}; permlane16_swap of that
    // pair -> d0={X.Q0,X.Q2,Y.Q0,Y.Q2}, d2={X.Q1,X.Q3,Y.Q1,Y.Q3}.
    s16x8 pa[2][2];
#pragma unroll
    for (int qs = 0; qs < 2; ++qs) {
      u32 w01[4], w23[4];
#pragma unroll
      for (int c = 0; c < 4; ++c) {
        w01[c] = pack_bf_trunc(__builtin_amdgcn_exp2f(s[qs][c][0]),
                               __builtin_amdgcn_exp2f(s[qs][c][1]));
        w23[c] = pack_bf_trunc(__builtin_amdgcn_exp2f(s[qs][c][2]),
                               __builtin_amdgcn_exp2f(s[qs][c][3]));
      }
#pragma unroll
      for (int ks = 0; ks < 2; ++ks) {
        u32x2 rA = __builtin_amdgcn_permlane32_swap(w01[2 * ks], w01[2 * ks + 1], false, false);
        u32x2 rB = __builtin_amdgcn_permlane16_swap(rA[0], rA[1], false, false);
        u32x2 rC = __builtin_amdgcn_permlane32_swap(w23[2 * ks], w23[2 * ks + 1], false, false);
        u32x2 rD = __builtin_amdgcn_permlane16_swap(rC[0], rC[1], false, false);
        const u32x4 pd = (u32x4){rB[0], rD[0], rB[1], rD[1]};
        pa[qs][ks] = __builtin_bit_cast(s16x8, pd);
      }
    }

    // O += P @ V ; ls += P @ ones  (8 LDS reads feed 20 MFMAs)
#pragma unroll
    for (int ks = 0; ks < 2; ++ks) {
#pragma unroll
      for (int d = 0; d < 4; ++d) {
        const int rowv = d * 16 + m15;
        const s16x8 bv = *(const s16x8*)&VTc[(rowv * 8 + ((ks * 4 + g) ^ (rowv & 7))) * 8];
        o[0][d] = MFMA16(pa[0][ks], bv, o[0][d]);
        o[1][d] = MFMA16(pa[1][ks], bv, o[1][d]);
      }
      ls4[0] = MFMA16(pa[0][ks], vone, ls4[0]);
      ls4[1] = MFMA16(pa[1][ks], vone, ls4[1]);
    }
    cur ^= 1;
  }
#undef STAGE

#pragma unroll
  for (int qs = 0; qs < 2; ++qs) {
    f32x4 inv;
#pragma unroll
    for (int r = 0; r < 4; ++r) inv[r] = 1.0f / ls4[qs][r];
    const int orow = b * 2048 + qw + qs * 16 + g * 4;
    const int ocol = h * 64 + m15;
#pragma unroll
    for (int d = 0; d < 4; ++d) {
#pragma unroll
      for (int r = 0; r < 4; ++r)
        CTX[(orow + r) * 1024 + ocol + d * 16] = f2bf(o[qs][d][r] * inv[r]);
    }
  }
}

// ---------------- launch ----------------

extern "C" void kernel_launch(void* const* d_in, const int* in_sizes, int n_in,
                              void* d_out, int out_size, void* d_ws, size_t ws_size,
                              hipStream_t stream) {
  (void)in_sizes; (void)n_in; (void)out_size; (void)ws_size;
  const float* hs  = (const float*)d_in[0];
  const float* Wq  = (const float*)d_in[1];
  const float* Wk  = (const float*)d_in[2];
  const float* Wv  = (const float*)d_in[3];
  const float* Wo  = (const float*)d_in[4];
  const float* tbl = (const float*)d_in[5];

  char* ws = (char*)d_ws;
  u16* hsb   = (u16*)(ws);                 // 8 MB  bf16 hidden
  u16* wt    = (u16*)(ws + 8388608);       // 6 MB  Wq^T|Wk^T|Wv^T bf16
  u16* wot   = (u16*)(ws + 14680064);      // 2 MB  Wo^T bf16
  u16* q     = (u16*)(ws + 16777216);      // 8 MB  Q bf16 (scaled)
  u16* k     = (u16*)(ws + 25165824);      // 8 MB  K bf16
  u16* v     = (u16*)(ws + 33554432);      // 8 MB  V bf16
  u16* vt    = (u16*)(ws + 41943040);      // 8 MB  V^T bf16 [32][64][2048]
  u16* ctx   = (u16*)(ws + 50331648);      // 8 MB  attn output bf16
  float* biasT = (float*)(ws + 58720256);  // 256 KB bias table [16][4096]

  prep<<<4352, 256, 0, stream>>>(hs, Wq, Wk, Wv, Wo, tbl, hsb, wt, wot, biasT);
  gemm_qkv<<<768, 256, 0, stream>>>(hsb, wt, q, k, v);
  vtrans<<<dim3(64, 32), 256, 0, stream>>>(v, vt);
  attn_kernel<<<512, 256, 0, stream>>>(q, k, vt, biasT, tbl, ctx);
  gemm_out<<<256, 256, 0, stream>>>(ctx, wot, (float*)d_out);
}